// Round 1
// 290.606 us; speedup vs baseline: 1.0006x; 1.0006x over previous
//
#include <hip/hip_runtime.h>

// MultinomialDiffusion.q_posterior — structure-exploiting, fully-coalesced version.
//   log_x_t : (16,2,1,1024,1024) f32  LOG ONE-HOT  -> read plane 0 only, hot = (val > -35)
//   log_x_0 : (16,2,1,1024,1024) f32  log-softmax  -> read plane 0 only (plane1 = log(1-p))
//   schedules (1000,) f32; t (16,) int32; out (16,2,1,1024,1024) f32
// Math per position (K=2), a = alpha_bar[t-1], c = (1-alpha_bar[t-1])/2:
//   p  = exp(l00); e0 = log(a*p + c); e1 = log(a*(1-p) + c)     [t>0]
//   d  = e0 - e1   (or l00 - l01 when t==0)
//   Delta = d + (hot0 ? +delta : -delta),  delta = logaddexp(C,D) - D
//   o0 = -logaddexp(0, -Delta),  o1 = o0 - Delta
//
// V2 change (latency → MLP): hoist ALL 8 input loads ahead of any NT store.
// The previous version's 16-VGPR schedule serialized load→compute→store per
// iteration, and the in-order vmcnt counter chained NT-store completion into
// the next iteration's load wait (observed: 2.47 TB/s, VALUBusy 30%,
// occupancy 70% — latency-bound). With loads all older than stores, load
// waits retire as soon as data returns; 8 KB in flight per wave.
// Register cost ~56 VGPR, still under the 64-VGPR full-occupancy step.

#define LL (1024 * 1024)
#define BLOCKS_PER_B 256              // 256 blocks x 256 thr x 4 iter x 4 elem = 2^20
#define ITER 4
#define STRIDE (BLOCKS_PER_B * 256)   // float4-groups per iteration step = 65536

typedef float vfloat4 __attribute__((ext_vector_type(4)));

__global__ __launch_bounds__(256) void qposterior_kernel(
    const float* __restrict__ lxt,
    const float* __restrict__ lx0,
    const float* __restrict__ la,
    const float* __restrict__ l1a,
    const float* __restrict__ lab,
    const float* __restrict__ l1ab,
    const int* __restrict__ tarr,
    float* __restrict__ out)
{
    const float LOGK = 0.6931471805599453f; // log(2)

    int bid   = blockIdx.x;
    int b     = bid >> 8;                 // 256 blocks per batch
    int local = bid & (BLOCKS_PER_B - 1);

    // ---- per-batch scalars (wave-uniform) ----
    int tb = tarr[b];
    bool t0 = (tb == 0);
    float C = la[tb];
    float D = l1a[tb] - LOGK;
    float mm = fmaxf(C, D);
    float s_hot = mm + __logf(1.0f + __expf(fminf(C, D) - mm));
    float delta = s_hot - D;              // logaddexp(C,D) - D

    float a = 0.f, c = 0.f, apc = 0.f;
    if (!t0) {
        int tm1 = tb - 1;
        a   = __expf(lab[tm1]);           // alpha_bar[t-1]
        c   = 0.5f * __expf(l1ab[tm1]);   // (1 - alpha_bar[t-1]) / 2
        apc = a + c;
    }

    const float* xt_p  = lxt + b * (2 * LL);
    const float* x0_p  = lx0 + b * (2 * LL);
    float*       out_p = out + b * (2 * LL);

    int g0 = local * 256 + threadIdx.x;   // float4-group index within batch plane

    if (!t0) {
        // ================= hot path (t > 0) =================
        // Phase 1: issue ALL loads (8 x 1KB/wave in flight, no store older
        // than any load -> vmcnt waits never chain on store completion).
        vfloat4 xt[ITER], x0[ITER];
#pragma unroll
        for (int it = 0; it < ITER; ++it) {
            int e = (g0 + it * STRIDE) * 4;
            xt[it] = *reinterpret_cast<const vfloat4*>(xt_p + e);
            x0[it] = *reinterpret_cast<const vfloat4*>(x0_p + e);
        }
        // Keep the compiler from sinking loads back down to save registers.
        __builtin_amdgcn_sched_barrier(0);

        // Phase 2: compute + NT stores (stores are youngest VMEM ops; they
        // drain in the background / at kernel end).
#pragma unroll
        for (int it = 0; it < ITER; ++it) {
            int e = (g0 + it * STRIDE) * 4;
            vfloat4 r0, r1;
#pragma unroll
            for (int i = 0; i < 4; ++i) {
                float l00 = x0[it][i];
                float p  = __expf(l00);
                float e0 = __logf(fmaf(a, p, c));
                float e1 = __logf(fmaf(-a, p, apc));
                float d  = e0 - e1;
                float sd    = (xt[it][i] > -35.0f) ? delta : -delta;
                float Delta = d + sd;
                // o0 = -logaddexp(0, -Delta)
                float m  = fmaxf(-Delta, 0.0f);
                float o0 = -(m + __logf(1.0f + __expf(-fabsf(Delta))));
                r0[i] = o0;
                r1[i] = o0 - Delta;
            }
            __builtin_nontemporal_store(r0, reinterpret_cast<vfloat4*>(out_p + e));
            __builtin_nontemporal_store(r1, reinterpret_cast<vfloat4*>(out_p + e + LL));
        }
    } else {
        // ================= t == 0 path (rare; uniform per batch) =================
        // d = log_x_0[class0] - log_x_0[class1]; needs plane-1 reads. Kept in a
        // separate uniform branch so its loads don't inflate hot-path registers.
#pragma unroll
        for (int it = 0; it < ITER; ++it) {
            int e = (g0 + it * STRIDE) * 4;
            vfloat4 xt = *reinterpret_cast<const vfloat4*>(xt_p + e);
            vfloat4 x0 = *reinterpret_cast<const vfloat4*>(x0_p + e);
            vfloat4 x1 = *reinterpret_cast<const vfloat4*>(x0_p + e + LL);
            vfloat4 r0, r1;
#pragma unroll
            for (int i = 0; i < 4; ++i) {
                float d = x0[i] - x1[i];
                float sd    = (xt[i] > -35.0f) ? delta : -delta;
                float Delta = d + sd;
                float m  = fmaxf(-Delta, 0.0f);
                float o0 = -(m + __logf(1.0f + __expf(-fabsf(Delta))));
                r0[i] = o0;
                r1[i] = o0 - Delta;
            }
            __builtin_nontemporal_store(r0, reinterpret_cast<vfloat4*>(out_p + e));
            __builtin_nontemporal_store(r1, reinterpret_cast<vfloat4*>(out_p + e + LL));
        }
    }
}

extern "C" void kernel_launch(void* const* d_in, const int* in_sizes, int n_in,
                              void* d_out, int out_size, void* d_ws, size_t ws_size,
                              hipStream_t stream) {
    const float* lxt  = (const float*)d_in[0];
    const float* lx0  = (const float*)d_in[1];
    const float* la   = (const float*)d_in[2];
    const float* l1a  = (const float*)d_in[3];
    const float* lab  = (const float*)d_in[4];
    const float* l1ab = (const float*)d_in[5];
    const int*   tarr = (const int*)d_in[6];
    float*       out  = (float*)d_out;

    const int grid  = 16 * BLOCKS_PER_B;  // 4096 blocks
    const int block = 256;

    qposterior_kernel<<<grid, block, 0, stream>>>(lxt, lx0, la, l1a, lab, l1ab, tarr, out);
}

// Round 2
// 288.769 us; speedup vs baseline: 1.0070x; 1.0064x over previous
//
#include <hip/hip_runtime.h>

// MultinomialDiffusion.q_posterior — structure-exploiting, fully-coalesced version.
//   log_x_t : (16,2,1,1024,1024) f32  LOG ONE-HOT  -> read plane 0 only, hot = (val > -35)
//   log_x_0 : (16,2,1,1024,1024) f32  log-softmax  -> read plane 0 only (plane1 = log(1-p))
//   schedules (1000,) f32; t (16,) int32; out (16,2,1,1024,1024) f32
// Math per position (K=2), a = alpha_bar[t-1], c = (1-alpha_bar[t-1])/2:
//   p  = exp(l00); e0 = log(a*p + c); e1 = log(a*(1-p) + c)     [t>0]
//   d  = e0 - e1   (or l00 - l01 when t==0)
//   Delta = d + (hot0 ? +delta : -delta),  delta = logaddexp(C,D) - D
//   o0 = -logaddexp(0, -Delta),  o1 = o0 - Delta
//
// V3 changes (service-rate theory):
//  * NORMAL write-back stores instead of nontemporal. V2 (load-hoist) was
//    ~neutral -> memory queues are saturated at 2.45 TB/s, i.e. the limit is
//    the SERVICE RATE of the NT read/write mix, not latency. Reference points
//    on this chip: fillBuffer (normal stores, pure write) = 6.8 TB/s; float4
//    copy (normal stores, R+W) = 6.3 TB/s; us with NT = 2.45 TB/s. Trade the
//    64MB L3 fetch saving for the 2.5x faster write path.
//  * Each block now covers a CONTIGUOUS 16KB run per stream (iterations
//    adjacent) instead of 4x4KB chunks 1MB apart -> better DRAM row locality.
//  * Load hoist + sched_barrier kept from V2 (harmless, slightly positive).

#define LL (1024 * 1024)
#define BLOCKS_PER_B 256              // 256 blocks x 256 thr x 4 iter x 4 elem = 2^20
#define ITER 4

typedef float vfloat4 __attribute__((ext_vector_type(4)));

__global__ __launch_bounds__(256) void qposterior_kernel(
    const float* __restrict__ lxt,
    const float* __restrict__ lx0,
    const float* __restrict__ la,
    const float* __restrict__ l1a,
    const float* __restrict__ lab,
    const float* __restrict__ l1ab,
    const int* __restrict__ tarr,
    float* __restrict__ out)
{
    const float LOGK = 0.6931471805599453f; // log(2)

    int bid   = blockIdx.x;
    int b     = bid >> 8;                 // 256 blocks per batch
    int local = bid & (BLOCKS_PER_B - 1);

    // ---- per-batch scalars (wave-uniform) ----
    int tb = tarr[b];
    bool t0 = (tb == 0);
    float C = la[tb];
    float D = l1a[tb] - LOGK;
    float mm = fmaxf(C, D);
    float s_hot = mm + __logf(1.0f + __expf(fminf(C, D) - mm));
    float delta = s_hot - D;              // logaddexp(C,D) - D

    float a = 0.f, c = 0.f, apc = 0.f;
    if (!t0) {
        int tm1 = tb - 1;
        a   = __expf(lab[tm1]);           // alpha_bar[t-1]
        c   = 0.5f * __expf(l1ab[tm1]);   // (1 - alpha_bar[t-1]) / 2
        apc = a + c;
    }

    const float* xt_p  = lxt + b * (2 * LL);
    const float* x0_p  = lx0 + b * (2 * LL);
    float*       out_p = out + b * (2 * LL);

    // Contiguous 16KB window per block: group index = local*1024 + it*256 + tid.
    int gbase = local * (ITER * 256) + threadIdx.x;

    if (!t0) {
        // ================= hot path (t > 0) =================
        // Phase 1: issue ALL loads (loads older than all stores -> vmcnt
        // waits on loads never chain behind store completion).
        vfloat4 xt[ITER], x0[ITER];
#pragma unroll
        for (int it = 0; it < ITER; ++it) {
            int e = (gbase + it * 256) * 4;
            xt[it] = *reinterpret_cast<const vfloat4*>(xt_p + e);
            x0[it] = *reinterpret_cast<const vfloat4*>(x0_p + e);
        }
        __builtin_amdgcn_sched_barrier(0);

        // Phase 2: compute + write-back stores.
#pragma unroll
        for (int it = 0; it < ITER; ++it) {
            int e = (gbase + it * 256) * 4;
            vfloat4 r0, r1;
#pragma unroll
            for (int i = 0; i < 4; ++i) {
                float l00 = x0[it][i];
                float p  = __expf(l00);
                float e0 = __logf(fmaf(a, p, c));
                float e1 = __logf(fmaf(-a, p, apc));
                float d  = e0 - e1;
                float sd    = (xt[it][i] > -35.0f) ? delta : -delta;
                float Delta = d + sd;
                // o0 = -logaddexp(0, -Delta)
                float m  = fmaxf(-Delta, 0.0f);
                float o0 = -(m + __logf(1.0f + __expf(-fabsf(Delta))));
                r0[i] = o0;
                r1[i] = o0 - Delta;
            }
            *reinterpret_cast<vfloat4*>(out_p + e)      = r0;
            *reinterpret_cast<vfloat4*>(out_p + e + LL) = r1;
        }
    } else {
        // ================= t == 0 path (rare; uniform per batch) =================
        // d = log_x_0[class0] - log_x_0[class1]; needs plane-1 reads. Kept in a
        // separate uniform branch so its loads don't inflate hot-path registers.
#pragma unroll
        for (int it = 0; it < ITER; ++it) {
            int e = (gbase + it * 256) * 4;
            vfloat4 xt = *reinterpret_cast<const vfloat4*>(xt_p + e);
            vfloat4 x0 = *reinterpret_cast<const vfloat4*>(x0_p + e);
            vfloat4 x1 = *reinterpret_cast<const vfloat4*>(x0_p + e + LL);
            vfloat4 r0, r1;
#pragma unroll
            for (int i = 0; i < 4; ++i) {
                float d = x0[i] - x1[i];
                float sd    = (xt[i] > -35.0f) ? delta : -delta;
                float Delta = d + sd;
                float m  = fmaxf(-Delta, 0.0f);
                float o0 = -(m + __logf(1.0f + __expf(-fabsf(Delta))));
                r0[i] = o0;
                r1[i] = o0 - Delta;
            }
            *reinterpret_cast<vfloat4*>(out_p + e)      = r0;
            *reinterpret_cast<vfloat4*>(out_p + e + LL) = r1;
        }
    }
}

extern "C" void kernel_launch(void* const* d_in, const int* in_sizes, int n_in,
                              void* d_out, int out_size, void* d_ws, size_t ws_size,
                              hipStream_t stream) {
    const float* lxt  = (const float*)d_in[0];
    const float* lx0  = (const float*)d_in[1];
    const float* la   = (const float*)d_in[2];
    const float* l1a  = (const float*)d_in[3];
    const float* lab  = (const float*)d_in[4];
    const float* l1ab = (const float*)d_in[5];
    const int*   tarr = (const int*)d_in[6];
    float*       out  = (float*)d_out;

    const int grid  = 16 * BLOCKS_PER_B;  // 4096 blocks
    const int block = 256;

    qposterior_kernel<<<grid, block, 0, stream>>>(lxt, lx0, la, l1a, lab, l1ab, tarr, out);
}